// Round 15
// baseline (97.493 us; speedup 1.0000x reference)
//
#include <hip/hip_runtime.h>
#include <hip/hip_bf16.h>
#include <cstdint>
#include <cstddef>

#define Bc 4
#define Lc 2048
#define Kc 30
#define Fc 416
#define Nc 128

typedef __bf16 bf16x8 __attribute__((ext_vector_type(8)));
typedef float  f32x4  __attribute__((ext_vector_type(4)));
typedef unsigned short ushortx8 __attribute__((ext_vector_type(8)));

// atom index map: N=0, C=1, Ca=2, Cb=3, O=4
__constant__ int c_pa[24] = {0,2,3,1,1,1,0,0,3,0,2,3,2,3,2,4,1,4,0,4,3,4,4,2};
__constant__ int c_pb[24] = {0,2,3,0,2,3,2,3,2,1,1,1,0,0,3,4,4,1,4,0,4,2,3,2};

__device__ __forceinline__ unsigned long long u64min(unsigned long long a, unsigned long long b) {
    return a < b ? a : b;
}
__device__ __forceinline__ unsigned long long u64max(unsigned long long a, unsigned long long b) {
    return a > b ? a : b;
}

__device__ __forceinline__ unsigned short f2bf(float f) {
    __hip_bfloat16 h = __float2bfloat16(f);
    return *(unsigned short*)&h;
}

// 8 RBF values starting at center mu0, spacing 4/3, sigma 1.25.
__device__ __forceinline__ void rbf8(float d, float mu0, float* v) {
    const float u0 = (d - mu0) * 0.8f;
    v[0] = __expf(-u0 * u0);
    float rr = __expf(fmaf(2.1333333f, u0, -1.1377778f));   // exp(2*dl*u0 - dl^2), dl=16/15
    #pragma unroll
    for (int m = 1; m < 8; ++m) {
        v[m] = v[m - 1] * rr;
        rr *= 0.10274083f;                                   // exp(-2*(16/15)^2)
    }
}

// 16-lane rotate-add reduce via DPP (row_ror:N), all lanes end with the sum.
template<int CTRL>
__device__ __forceinline__ float dpp_radd(float x) {
    const int r = __builtin_amdgcn_update_dpp(0, __float_as_int(x), CTRL, 0xf, 0xf, true);
    return x + __int_as_float(r);
}
__device__ __forceinline__ float row16_sum(float x) {
    x = dpp_radd<0x121>(x);   // ror 1
    x = dpp_radd<0x122>(x);   // ror 2
    x = dpp_radd<0x124>(x);   // ror 4
    x = dpp_radd<0x128>(x);   // ror 8
    return x;
}

// ---------------- Kernel 1: top-k (blocks <1024) + W-prep (blocks >=1024) ---
// topk: 8 rows/block, batch C-slice staged in LDS. W-prep: 104 blocks x 512
// threads transpose edge_w -> bf16 Wt[n][k] (consumed by edge_mfma8 later).
__global__ __launch_bounds__(512) void topk5(
    const float* __restrict__ X, const float* __restrict__ mask,
    const float* __restrict__ Wg, unsigned short* __restrict__ Wt,
    int* __restrict__ eidx, float* __restrict__ dnb, float* __restrict__ outEidx)
{
#pragma clang fp contract(off)
    if (blockIdx.x >= 1024) {                  // ---- W transpose tail blocks ----
        const int id = (blockIdx.x - 1024) * 512 + threadIdx.x;  // 104*512 = 53248
        const int n = id / Fc, k = id - n * Fc;
        Wt[id] = f2bf(Wg[k * Nc + n]);
        return;
    }

    __shared__ float4 cp[Lc];                  // 32 KB packed C+mask for the batch
    __shared__ unsigned long long pairs[8][256];
    __shared__ int scnt[8];

    const int t = threadIdx.x;                 // 0..511
    const int lane = t & 63, wv = t >> 6;
    const int row = blockIdx.x * 8 + wv;       // b*L + i
    const int b   = blockIdx.x >> 8;           // 256 blocks per batch

    // --- stage packed batch slice ---
    #pragma unroll
    for (int s = 0; s < 4; ++s) {
        const int j = s * 512 + t;
        const float* p = X + (size_t)(b * Lc + j) * 12;
        float4 o;
        o.x = p[3]; o.y = p[4]; o.z = p[5];
        o.w = mask[b * Lc + j];
        cp[j] = o;
    }
    if (lane == 0) scnt[wv] = 0;
    __syncthreads();                           // the kernel's only barrier

    const float4 ci = cp[row & (Lc - 1)];
    const float cix = ci.x, ciy = ci.y, ciz = ci.z, mi = ci.w;

    // pass 1: distances from LDS, wave max
    float D[32], am[32];
    float dmax = -1e30f;
    #pragma unroll 8
    for (int s = 0; s < 32; ++s) {
        const float4 f4 = cp[s * 64 + lane];
        const float dx = f4.x - cix;
        const float dy = f4.y - ciy;
        const float dz = f4.z - ciz;
        const float ss = dx * dx + dy * dy + dz * dz;
        const float dist = sqrtf(ss + 1e-6f);
        const float m2 = mi * f4.w;
        D[s] = m2 * dist;
        am[s] = 1.0f - m2;
        dmax = fmaxf(dmax, D[s]);
    }
    #pragma unroll
    for (int off = 32; off; off >>= 1) dmax = fmaxf(dmax, __shfl_xor(dmax, off, 64));

    // pass 2: Dadj bits in registers; per-lane min key
    unsigned uv[32];
    unsigned long long lmin = ~0ULL;
    #pragma unroll 8
    for (int s = 0; s < 32; ++s) {
        const float Dadj = D[s] + am[s] * dmax;
        uv[s] = __float_as_uint(Dadj);
        const unsigned long long k =
            ((unsigned long long)uv[s] << 32) | (unsigned)(s * 64 + lane);
        lmin = u64min(lmin, k);
    }

    // bitonic sort of the 64 lane-min keys (ascending across lanes)
    unsigned long long sv = lmin;
    #pragma unroll
    for (int k = 2; k <= 64; k <<= 1) {
        #pragma unroll
        for (int j = k >> 1; j > 0; j >>= 1) {
            const unsigned long long o =
                (unsigned long long)__shfl_xor((long long)sv, j, 64);
            const bool takeMin = (((lane & k) == 0) == ((lane & j) == 0));
            sv = takeMin ? u64min(sv, o) : u64max(sv, o);
        }
    }
    const unsigned long long Tkey =
        (unsigned long long)__shfl((long long)sv, 29, 64);

    // gather survivors (key <= Tkey) into this wave's LDS list
    #pragma unroll 8
    for (int s = 0; s < 32; ++s) {
        const unsigned long long key =
            ((unsigned long long)uv[s] << 32) | (unsigned)(s * 64 + lane);
        if (key <= Tkey) {
            const int pos = atomicAdd(&scnt[wv], 1);
            if (pos < 256) pairs[wv][pos] = key;
        }
    }
    const int S = min(scnt[wv], 256);

    // exact rank among survivors; rank < 30 -> output slot = rank
    for (int p = lane; p < S; p += 64) {
        const unsigned long long kp = pairs[wv][p];
        int r = 0;
        for (int q = 0; q < S; ++q)
            r += (pairs[wv][q] < kp) ? 1 : 0;
        if (r < Kc) {
            const int j = (int)(kp & 0xffffffffULL);
            eidx[row * Kc + r] = j;
            dnb[row * Kc + r] = __uint_as_float((unsigned)(kp >> 32));
            outEidx[(size_t)row * Kc + r] = (float)j;
        }
    }
}

// ---------------- Kernel 2: BK=64 (2 chunks/barrier) MFMA GEMM + LayerNorm --
// block = 8 residues (240 edges, M=256), 1024 blocks, 512 threads / 8 waves.
// 7 barrier intervals instead of 13: each interval does 2 K-chunks of
// independent {ds_read x16, MFMA x32, afrag x4} work.
__global__ __launch_bounds__(512, 4) void edge_mfma8(
    const float* __restrict__ X, const int* __restrict__ ridx, const int* __restrict__ clab,
    const float* __restrict__ pe_w, const float* __restrict__ pe_b,
    const unsigned short* __restrict__ Wt,   // bf16 [128][416] (n-major)
    const float* __restrict__ ln_g, const float* __restrict__ ln_b,
    const int* __restrict__ eidx, const float* __restrict__ dnb,
    float* __restrict__ outE)
{
    __shared__ unsigned short Bs[2][2][8][512]; // [buf][slot][n-tile][lane*8], 32 KB
    __shared__ float atomsA[8][17];
    __shared__ float atomsB[240][17];
    __shared__ float dnb_s[240];
    __shared__ int   pid_s[240];

    const int blk = blockIdx.x;              // 1024
    const int t   = threadIdx.x;             // 0..511
    const int lane = t & 63, wv = t >> 6;    // 8 waves
    const int b   = blk >> 8;                // 256 blocks per batch
    const int cl  = lane & 15, q = lane >> 4;

    // --- staging: atoms + Cb for 8 residues and their 240 neighbors ---
    if (t < 248) {
        int j;
        float* dst;
        if (t < 240) {
            j = eidx[(blk * 8 + t / 30) * Kc + (t % 30)];
            dst = &atomsB[t][0];
            dnb_s[t] = dnb[(blk * 8 + t / 30) * Kc + (t % 30)];
            const int rowi = blk * 8 + t / 30;
            const int jg = b * Lc + j;
            const int off = ridx[rowi] - ridx[jg];
            const int ec  = (clab[rowi] == clab[jg]) ? 1 : 0;
            pid_s[t] = ec ? min(max(off + 32, 0), 64) : 65;
        } else {
            j = (blk * 8 + (t - 240)) & (Lc - 1);
            dst = &atomsA[t - 240][0];
        }
        const float* p = X + (size_t)(b * Lc + j) * 12;
        const float Nx = p[0],  Ny = p[1],  Nz = p[2];
        const float Cx = p[3],  Cy = p[4],  Cz = p[5];
        const float Cax = p[6], Cay = p[7], Caz = p[8];
        const float Ox = p[9],  Oy = p[10], Oz = p[11];
        const float bx = Cax - Nx, by = Cay - Ny, bz = Caz - Nz;
        const float cx = Cx - Cax, cy = Cy - Cay, cz = Cz - Caz;
        const float ax = by * cz - bz * cy;
        const float ay = bz * cx - bx * cz;
        const float az = bx * cy - by * cx;
        dst[0] = Nx;  dst[1] = Ny;  dst[2] = Nz;
        dst[3] = Cx;  dst[4] = Cy;  dst[5] = Cz;
        dst[6] = Cax; dst[7] = Cay; dst[8] = Caz;
        dst[9]  = -0.58273431f * ax + 0.56802827f * bx - 0.54067466f * cx + Cax;
        dst[10] = -0.58273431f * ay + 0.56802827f * by - 0.54067466f * cy + Cay;
        dst[11] = -0.58273431f * az + 0.56802827f * bz - 0.54067466f * cz + Caz;
        dst[12] = Ox; dst[13] = Oy; dst[14] = Oz;
    }

    // --- B staging: wave wv covers n-tile wv; chunks kc at gW + kc*32 ---
    const unsigned short* gW = Wt + (wv * 16 + cl) * Fc + q * 8;
    {
        *(ushortx8*)&Bs[0][0][wv][lane * 8] = *(const ushortx8*)gW;          // chunk 0
        *(ushortx8*)&Bs[0][1][wv][lane * 8] = *(const ushortx8*)(gW + 32);   // chunk 1
    }
    __syncthreads();

    f32x4 acc[2][8];
    #pragma unroll
    for (int m = 0; m < 2; ++m)
        #pragma unroll
        for (int n = 0; n < 8; ++n) acc[m][n] = (f32x4){0.f, 0.f, 0.f, 0.f};

    const int row0 = wv * 32 + cl;
    const int row1 = row0 + 16;
    const int e0 = min(row0, 239), e1 = min(row1, 239);
    const int r0 = e0 / 30,        r1 = e1 / 30;

    auto afrag = [&](int kc, int e, int r) -> bf16x8 {
        float v[8];
        if (kc == 0) {
            if (q < 2) {
                const int base = pid_s[e] * 16 + q * 8;
                const float4 p0 = *(const float4*)&pe_w[base];
                const float4 p1 = *(const float4*)&pe_w[base + 4];
                const float4 b0 = *(const float4*)&pe_b[q * 8];
                const float4 b1 = *(const float4*)&pe_b[q * 8 + 4];
                v[0] = p0.x + b0.x; v[1] = p0.y + b0.y;
                v[2] = p0.z + b0.z; v[3] = p0.w + b0.w;
                v[4] = p1.x + b1.x; v[5] = p1.y + b1.y;
                v[6] = p1.z + b1.z; v[7] = p1.w + b1.w;
            } else {
                rbf8(dnb_s[e], (q == 2) ? 2.0f : 12.6666667f, v);
            }
        } else {
            const int p  = 2 * kc - 2 + (q >> 1);
            const int a_ = c_pa[p], b_ = c_pb[p];
            const float dx = atomsA[r][a_ * 3 + 0] - atomsB[e][b_ * 3 + 0];
            const float dy = atomsA[r][a_ * 3 + 1] - atomsB[e][b_ * 3 + 1];
            const float dz = atomsA[r][a_ * 3 + 2] - atomsB[e][b_ * 3 + 2];
            const float d = sqrtf(dx * dx + dy * dy + dz * dz + 1e-6f);
            rbf8(d, (q & 1) ? 12.6666667f : 2.0f, v);
        }
        ushortx8 o;
        #pragma unroll
        for (int m = 0; m < 8; ++m) o[m] = f2bf(v[m]);
        return __builtin_bit_cast(bf16x8, o);
    };

    bf16x8 a0c = afrag(0, e0, r0);
    bf16x8 a1c = afrag(0, e1, r1);

    for (int iv = 0; iv < 7; ++iv) {         // 7 barrier intervals, 2 chunks each
        const int cur = iv & 1;
        const int kcA = 2 * iv;
        const bool hasB = (kcA + 1) <= 12;
        ushortx8 st0, st1;
        if (iv < 6) {                         // issue next interval's loads early
            st0 = *(const ushortx8*)(gW + (kcA + 2) * 32);
            st1 = *(const ushortx8*)(gW + (kcA + 3) * 32);
        }
        // a-frags for chunk B overlap chunk A's MFMAs
        bf16x8 a0n, a1n;
        if (hasB) {
            a0n = afrag(kcA + 1, e0, r0);
            a1n = afrag(kcA + 1, e1, r1);
        }
        #pragma unroll
        for (int n = 0; n < 8; ++n) {
            const bf16x8 bb = __builtin_bit_cast(bf16x8,
                *(const ushortx8*)&Bs[cur][0][n][lane * 8]);
            acc[0][n] = __builtin_amdgcn_mfma_f32_16x16x32_bf16(a0c, bb, acc[0][n], 0, 0, 0);
            acc[1][n] = __builtin_amdgcn_mfma_f32_16x16x32_bf16(a1c, bb, acc[1][n], 0, 0, 0);
        }
        if (hasB) {
            // a-frags for next interval's chunk A overlap chunk B's MFMAs
            bf16x8 a0m, a1m;
            if (iv < 6) {
                a0m = afrag(kcA + 2, e0, r0);
                a1m = afrag(kcA + 2, e1, r1);
            }
            #pragma unroll
            for (int n = 0; n < 8; ++n) {
                const bf16x8 bb = __builtin_bit_cast(bf16x8,
                    *(const ushortx8*)&Bs[cur][1][n][lane * 8]);
                acc[0][n] = __builtin_amdgcn_mfma_f32_16x16x32_bf16(a0n, bb, acc[0][n], 0, 0, 0);
                acc[1][n] = __builtin_amdgcn_mfma_f32_16x16x32_bf16(a1n, bb, acc[1][n], 0, 0, 0);
            }
            a0c = a0m; a1c = a1m;
        }
        if (iv < 6) {                         // write-late
            *(ushortx8*)&Bs[cur ^ 1][0][wv][lane * 8] = st0;
            *(ushortx8*)&Bs[cur ^ 1][1][wv][lane * 8] = st1;
        }
        __syncthreads();
    }

    // ---------------- LayerNorm (DPP rotate-reduce) + store ----------------
    float gcol[8], bcol[8];
    #pragma unroll
    for (int n = 0; n < 8; ++n) {
        gcol[n] = ln_g[n * 16 + cl];
        bcol[n] = ln_b[n * 16 + cl];
    }
    #pragma unroll
    for (int m = 0; m < 2; ++m) {
        #pragma unroll
        for (int reg = 0; reg < 4; ++reg) {
            const int rl = wv * 32 + m * 16 + q * 4 + reg;
            float s1 = 0.f, s2 = 0.f;
            #pragma unroll
            for (int n = 0; n < 8; ++n) {
                const float v = acc[m][n][reg];
                s1 += v; s2 += v * v;
            }
            s1 = row16_sum(s1);
            s2 = row16_sum(s2);
            if (rl < 240) {
                const float mu = s1 * (1.0f / 128.0f);
                const float var = s2 * (1.0f / 128.0f) - mu * mu;
                const float rstd = rsqrtf(var + 1e-5f);
                const size_t base = ((size_t)(blk * 240 + rl)) * 128 + cl;
                #pragma unroll
                for (int n = 0; n < 8; ++n) {
                    outE[base + n * 16] =
                        (acc[m][n][reg] - mu) * rstd * gcol[n] + bcol[n];
                }
            }
        }
    }
}

extern "C" void kernel_launch(void* const* d_in, const int* in_sizes, int n_in,
                              void* d_out, int out_size, void* d_ws, size_t ws_size,
                              hipStream_t stream) {
    const float* X     = (const float*)d_in[0];
    const float* mask  = (const float*)d_in[1];
    const int*   ridx  = (const int*)d_in[2];
    const int*   clab  = (const int*)d_in[3];
    const float* pe_w  = (const float*)d_in[4];
    const float* pe_b  = (const float*)d_in[5];
    const float* edge_w = (const float*)d_in[6];
    const float* ln_g  = (const float*)d_in[7];
    const float* ln_b  = (const float*)d_in[8];

    float* outE   = (float*)d_out;
    float* outIdx = outE + (size_t)Bc * Lc * Kc * Nc;   // E_idx region (as float)

    char* ws = (char*)d_ws;
    int*   eidx = (int*)ws;                                  //   983,040 B
    float* dnbw = (float*)(ws + 983040);                     //   983,040 B
    unsigned short* Wt = (unsigned short*)(ws + 1966080);    //   106,496 B

    topk5<<<1024 + 104, 512, 0, stream>>>(X, mask, edge_w, Wt, eidx, dnbw, outIdx);
    edge_mfma8<<<Bc * Lc / 8, 512, 0, stream>>>(X, ridx, clab, pe_w, pe_b, Wt,
                                                ln_g, ln_b, eidx, dnbw, outE);
}

// Round 16
// 87.946 us; speedup vs baseline: 1.1086x; 1.1086x over previous
//
#include <hip/hip_runtime.h>
#include <hip/hip_bf16.h>
#include <cstdint>
#include <cstddef>

#define Bc 4
#define Lc 2048
#define Kc 30
#define Fc 416
#define Nc 128

typedef __bf16 bf16x8 __attribute__((ext_vector_type(8)));
typedef float  f32x4  __attribute__((ext_vector_type(4)));
typedef unsigned short ushortx8 __attribute__((ext_vector_type(8)));

// atom index map: N=0, C=1, Ca=2, Cb=3, O=4
__constant__ int c_pa[24] = {0,2,3,1,1,1,0,0,3,0,2,3,2,3,2,4,1,4,0,4,3,4,4,2};
__constant__ int c_pb[24] = {0,2,3,0,2,3,2,3,2,1,1,1,0,0,3,4,4,1,4,0,4,2,3,2};

__device__ __forceinline__ unsigned long long u64min(unsigned long long a, unsigned long long b) {
    return a < b ? a : b;
}
__device__ __forceinline__ unsigned long long u64max(unsigned long long a, unsigned long long b) {
    return a > b ? a : b;
}

__device__ __forceinline__ unsigned short f2bf(float f) {
    __hip_bfloat16 h = __float2bfloat16(f);
    return *(unsigned short*)&h;
}

// 8 RBF values starting at center mu0, spacing 4/3, sigma 1.25.
__device__ __forceinline__ void rbf8(float d, float mu0, float* v) {
    const float u0 = (d - mu0) * 0.8f;
    v[0] = __expf(-u0 * u0);
    float rr = __expf(fmaf(2.1333333f, u0, -1.1377778f));   // exp(2*dl*u0 - dl^2), dl=16/15
    #pragma unroll
    for (int m = 1; m < 8; ++m) {
        v[m] = v[m - 1] * rr;
        rr *= 0.10274083f;                                   // exp(-2*(16/15)^2)
    }
}

// 16-lane rotate-add reduce via DPP (row_ror:N), all lanes end with the sum.
template<int CTRL>
__device__ __forceinline__ float dpp_radd(float x) {
    const int r = __builtin_amdgcn_update_dpp(0, __float_as_int(x), CTRL, 0xf, 0xf, true);
    return x + __int_as_float(r);
}
__device__ __forceinline__ float row16_sum(float x) {
    x = dpp_radd<0x121>(x);   // ror 1
    x = dpp_radd<0x122>(x);   // ror 2
    x = dpp_radd<0x124>(x);   // ror 4
    x = dpp_radd<0x128>(x);   // ror 8
    return x;
}

// ---------------- Kernel 1: top-k (blocks <1024) + W-prep (blocks >=1024) ---
__global__ __launch_bounds__(512) void topk5(
    const float* __restrict__ X, const float* __restrict__ mask,
    const float* __restrict__ Wg, unsigned short* __restrict__ Wt,
    int* __restrict__ eidx, float* __restrict__ dnb, float* __restrict__ outEidx)
{
#pragma clang fp contract(off)
    if (blockIdx.x >= 1024) {                  // ---- W transpose tail blocks ----
        const int id = (blockIdx.x - 1024) * 512 + threadIdx.x;  // 104*512 = 53248
        const int n = id / Fc, k = id - n * Fc;
        Wt[id] = f2bf(Wg[k * Nc + n]);
        return;
    }

    __shared__ float4 cp[Lc];                  // 32 KB packed C+mask for the batch
    __shared__ unsigned long long pairs[8][256];
    __shared__ int scnt[8];

    const int t = threadIdx.x;                 // 0..511
    const int lane = t & 63, wv = t >> 6;
    const int row = blockIdx.x * 8 + wv;       // b*L + i
    const int b   = blockIdx.x >> 8;           // 256 blocks per batch

    // --- stage packed batch slice ---
    #pragma unroll
    for (int s = 0; s < 4; ++s) {
        const int j = s * 512 + t;
        const float* p = X + (size_t)(b * Lc + j) * 12;
        float4 o;
        o.x = p[3]; o.y = p[4]; o.z = p[5];
        o.w = mask[b * Lc + j];
        cp[j] = o;
    }
    if (lane == 0) scnt[wv] = 0;
    __syncthreads();                           // the kernel's only barrier

    const float4 ci = cp[row & (Lc - 1)];
    const float cix = ci.x, ciy = ci.y, ciz = ci.z, mi = ci.w;

    // pass 1: distances from LDS, wave max
    float D[32], am[32];
    float dmax = -1e30f;
    #pragma unroll 8
    for (int s = 0; s < 32; ++s) {
        const float4 f4 = cp[s * 64 + lane];
        const float dx = f4.x - cix;
        const float dy = f4.y - ciy;
        const float dz = f4.z - ciz;
        const float ss = dx * dx + dy * dy + dz * dz;
        const float dist = sqrtf(ss + 1e-6f);
        const float m2 = mi * f4.w;
        D[s] = m2 * dist;
        am[s] = 1.0f - m2;
        dmax = fmaxf(dmax, D[s]);
    }
    #pragma unroll
    for (int off = 32; off; off >>= 1) dmax = fmaxf(dmax, __shfl_xor(dmax, off, 64));

    // pass 2: Dadj bits in registers; per-lane min key
    unsigned uv[32];
    unsigned long long lmin = ~0ULL;
    #pragma unroll 8
    for (int s = 0; s < 32; ++s) {
        const float Dadj = D[s] + am[s] * dmax;
        uv[s] = __float_as_uint(Dadj);
        const unsigned long long k =
            ((unsigned long long)uv[s] << 32) | (unsigned)(s * 64 + lane);
        lmin = u64min(lmin, k);
    }

    // bitonic sort of the 64 lane-min keys (ascending across lanes)
    unsigned long long sv = lmin;
    #pragma unroll
    for (int k = 2; k <= 64; k <<= 1) {
        #pragma unroll
        for (int j = k >> 1; j > 0; j >>= 1) {
            const unsigned long long o =
                (unsigned long long)__shfl_xor((long long)sv, j, 64);
            const bool takeMin = (((lane & k) == 0) == ((lane & j) == 0));
            sv = takeMin ? u64min(sv, o) : u64max(sv, o);
        }
    }
    const unsigned long long Tkey =
        (unsigned long long)__shfl((long long)sv, 29, 64);

    // gather survivors (key <= Tkey) into this wave's LDS list
    #pragma unroll 8
    for (int s = 0; s < 32; ++s) {
        const unsigned long long key =
            ((unsigned long long)uv[s] << 32) | (unsigned)(s * 64 + lane);
        if (key <= Tkey) {
            const int pos = atomicAdd(&scnt[wv], 1);
            if (pos < 256) pairs[wv][pos] = key;
        }
    }
    const int S = min(scnt[wv], 256);

    // exact rank among survivors; rank < 30 -> output slot = rank
    for (int p = lane; p < S; p += 64) {
        const unsigned long long kp = pairs[wv][p];
        int r = 0;
        for (int q = 0; q < S; ++q)
            r += (pairs[wv][q] < kp) ? 1 : 0;
        if (r < Kc) {
            const int j = (int)(kp & 0xffffffffULL);
            eidx[row * Kc + r] = j;
            dnb[row * Kc + r] = __uint_as_float((unsigned)(kp >> 32));
            outEidx[(size_t)row * Kc + r] = (float)j;
        }
    }
}

// ---------------- Kernel 2: 8-wave, 2-Mtile/wave MFMA GEMM + LayerNorm ------
// block = 8 residues (240 edges, M=256), 1024 blocks, 512 threads / 8 waves.
// Wave wv owns rows wv*32..wv*32+31 (two 16-row M-tiles) and all 8 N-tiles.
__global__ __launch_bounds__(512, 4) void edge_mfma7(
    const float* __restrict__ X, const int* __restrict__ ridx, const int* __restrict__ clab,
    const float* __restrict__ pe_w, const float* __restrict__ pe_b,
    const unsigned short* __restrict__ Wt,   // bf16 [128][416] (n-major)
    const float* __restrict__ ln_g, const float* __restrict__ ln_b,
    const int* __restrict__ eidx, const float* __restrict__ dnb,
    float* __restrict__ outE)
{
    __shared__ unsigned short Bs[2][8][512]; // [buf][n-tile][lane*8]
    __shared__ float atomsA[8][17];
    __shared__ float atomsB[240][17];
    __shared__ float dnb_s[240];
    __shared__ int   pid_s[240];

    const int blk = blockIdx.x;              // 1024
    const int t   = threadIdx.x;             // 0..511
    const int lane = t & 63, wv = t >> 6;    // 8 waves
    const int b   = blk >> 8;                // 256 blocks per batch
    const int cl  = lane & 15, q = lane >> 4;

    // --- staging: atoms + Cb for 8 residues and their 240 neighbors ---
    if (t < 248) {
        int j;
        float* dst;
        if (t < 240) {
            j = eidx[(blk * 8 + t / 30) * Kc + (t % 30)];
            dst = &atomsB[t][0];
            dnb_s[t] = dnb[(blk * 8 + t / 30) * Kc + (t % 30)];
            const int rowi = blk * 8 + t / 30;
            const int jg = b * Lc + j;
            const int off = ridx[rowi] - ridx[jg];
            const int ec  = (clab[rowi] == clab[jg]) ? 1 : 0;
            pid_s[t] = ec ? min(max(off + 32, 0), 64) : 65;
        } else {
            j = (blk * 8 + (t - 240)) & (Lc - 1);
            dst = &atomsA[t - 240][0];
        }
        const float* p = X + (size_t)(b * Lc + j) * 12;
        const float Nx = p[0],  Ny = p[1],  Nz = p[2];
        const float Cx = p[3],  Cy = p[4],  Cz = p[5];
        const float Cax = p[6], Cay = p[7], Caz = p[8];
        const float Ox = p[9],  Oy = p[10], Oz = p[11];
        const float bx = Cax - Nx, by = Cay - Ny, bz = Caz - Nz;
        const float cx = Cx - Cax, cy = Cy - Cay, cz = Cz - Caz;
        const float ax = by * cz - bz * cy;
        const float ay = bz * cx - bx * cz;
        const float az = bx * cy - by * cx;
        dst[0] = Nx;  dst[1] = Ny;  dst[2] = Nz;
        dst[3] = Cx;  dst[4] = Cy;  dst[5] = Cz;
        dst[6] = Cax; dst[7] = Cay; dst[8] = Caz;
        dst[9]  = -0.58273431f * ax + 0.56802827f * bx - 0.54067466f * cx + Cax;
        dst[10] = -0.58273431f * ay + 0.56802827f * by - 0.54067466f * cy + Cay;
        dst[11] = -0.58273431f * az + 0.56802827f * bz - 0.54067466f * cz + Caz;
        dst[12] = Ox; dst[13] = Oy; dst[14] = Oz;
    }

    // --- B staging geometry: wave wv stages n-tile wv, one 16B frag/thread ---
    const unsigned short* gW = Wt + (wv * 16 + cl) * Fc + q * 8;
    {
        *(ushortx8*)&Bs[0][wv][lane * 8] = *(const ushortx8*)gW;   // chunk 0
    }
    __syncthreads();

    f32x4 acc[2][8];
    #pragma unroll
    for (int m = 0; m < 2; ++m)
        #pragma unroll
        for (int n = 0; n < 8; ++n) acc[m][n] = (f32x4){0.f, 0.f, 0.f, 0.f};

    const int row0 = wv * 32 + cl;
    const int row1 = row0 + 16;
    const int e0 = min(row0, 239), e1 = min(row1, 239);
    const int r0 = e0 / 30,        r1 = e1 / 30;

    auto afrag = [&](int kc, int e, int r) -> bf16x8 {
        float v[8];
        if (kc == 0) {
            if (q < 2) {
                const int base = pid_s[e] * 16 + q * 8;
                const float4 p0 = *(const float4*)&pe_w[base];
                const float4 p1 = *(const float4*)&pe_w[base + 4];
                const float4 b0 = *(const float4*)&pe_b[q * 8];
                const float4 b1 = *(const float4*)&pe_b[q * 8 + 4];
                v[0] = p0.x + b0.x; v[1] = p0.y + b0.y;
                v[2] = p0.z + b0.z; v[3] = p0.w + b0.w;
                v[4] = p1.x + b1.x; v[5] = p1.y + b1.y;
                v[6] = p1.z + b1.z; v[7] = p1.w + b1.w;
            } else {
                rbf8(dnb_s[e], (q == 2) ? 2.0f : 12.6666667f, v);
            }
        } else {
            const int p  = 2 * kc - 2 + (q >> 1);
            const int a_ = c_pa[p], b_ = c_pb[p];
            const float dx = atomsA[r][a_ * 3 + 0] - atomsB[e][b_ * 3 + 0];
            const float dy = atomsA[r][a_ * 3 + 1] - atomsB[e][b_ * 3 + 1];
            const float dz = atomsA[r][a_ * 3 + 2] - atomsB[e][b_ * 3 + 2];
            const float d = sqrtf(dx * dx + dy * dy + dz * dz + 1e-6f);
            rbf8(d, (q & 1) ? 12.6666667f : 2.0f, v);
        }
        ushortx8 o;
        #pragma unroll
        for (int m = 0; m < 8; ++m) o[m] = f2bf(v[m]);
        return __builtin_bit_cast(bf16x8, o);
    };

    bf16x8 a0c = afrag(0, e0, r0);
    bf16x8 a1c = afrag(0, e1, r1);

    for (int kc = 0; kc < 13; ++kc) {
        const int cur = kc & 1;
        ushortx8 st;
        bf16x8 a0n, a1n;
        if (kc < 12) {
            st = *(const ushortx8*)(gW + (kc + 1) * 32);   // VMEM early
            a0n = afrag(kc + 1, e0, r0);                   // VALU overlaps MFMA
            a1n = afrag(kc + 1, e1, r1);
        }
        #pragma unroll
        for (int n = 0; n < 8; ++n) {
            const bf16x8 bb = __builtin_bit_cast(bf16x8,
                *(const ushortx8*)&Bs[cur][n][lane * 8]);
            acc[0][n] = __builtin_amdgcn_mfma_f32_16x16x32_bf16(a0c, bb, acc[0][n], 0, 0, 0);
            acc[1][n] = __builtin_amdgcn_mfma_f32_16x16x32_bf16(a1c, bb, acc[1][n], 0, 0, 0);
        }
        if (kc < 12) {                        // write-late
            *(ushortx8*)&Bs[cur ^ 1][wv][lane * 8] = st;
        }
        __syncthreads();
        a0c = a0n; a1c = a1n;
    }

    // ---------------- LayerNorm (DPP rotate-reduce) + store ----------------
    float gcol[8], bcol[8];
    #pragma unroll
    for (int n = 0; n < 8; ++n) {
        gcol[n] = ln_g[n * 16 + cl];
        bcol[n] = ln_b[n * 16 + cl];
    }
    #pragma unroll
    for (int m = 0; m < 2; ++m) {
        #pragma unroll
        for (int reg = 0; reg < 4; ++reg) {
            const int rl = wv * 32 + m * 16 + q * 4 + reg;
            float s1 = 0.f, s2 = 0.f;
            #pragma unroll
            for (int n = 0; n < 8; ++n) {
                const float v = acc[m][n][reg];
                s1 += v; s2 += v * v;
            }
            s1 = row16_sum(s1);
            s2 = row16_sum(s2);
            if (rl < 240) {
                const float mu = s1 * (1.0f / 128.0f);
                const float var = s2 * (1.0f / 128.0f) - mu * mu;
                const float rstd = rsqrtf(var + 1e-5f);
                const size_t base = ((size_t)(blk * 240 + rl)) * 128 + cl;
                #pragma unroll
                for (int n = 0; n < 8; ++n) {
                    outE[base + n * 16] =
                        (acc[m][n][reg] - mu) * rstd * gcol[n] + bcol[n];
                }
            }
        }
    }
}

extern "C" void kernel_launch(void* const* d_in, const int* in_sizes, int n_in,
                              void* d_out, int out_size, void* d_ws, size_t ws_size,
                              hipStream_t stream) {
    const float* X     = (const float*)d_in[0];
    const float* mask  = (const float*)d_in[1];
    const int*   ridx  = (const int*)d_in[2];
    const int*   clab  = (const int*)d_in[3];
    const float* pe_w  = (const float*)d_in[4];
    const float* pe_b  = (const float*)d_in[5];
    const float* edge_w = (const float*)d_in[6];
    const float* ln_g  = (const float*)d_in[7];
    const float* ln_b  = (const float*)d_in[8];

    float* outE   = (float*)d_out;
    float* outIdx = outE + (size_t)Bc * Lc * Kc * Nc;   // E_idx region (as float)

    char* ws = (char*)d_ws;
    int*   eidx = (int*)ws;                                  //   983,040 B
    float* dnbw = (float*)(ws + 983040);                     //   983,040 B
    unsigned short* Wt = (unsigned short*)(ws + 1966080);    //   106,496 B

    topk5<<<1024 + 104, 512, 0, stream>>>(X, mask, edge_w, Wt, eidx, dnbw, outIdx);
    edge_mfma7<<<Bc * Lc / 8, 512, 0, stream>>>(X, ridx, clab, pe_w, pe_b, Wt,
                                                ln_g, ln_b, eidx, dnbw, outE);
}

// Round 17
// 87.726 us; speedup vs baseline: 1.1113x; 1.0025x over previous
//
#include <hip/hip_runtime.h>
#include <hip/hip_bf16.h>
#include <cstdint>
#include <cstddef>

#define Bc 4
#define Lc 2048
#define Kc 30
#define Fc 416
#define Nc 128

typedef __bf16 bf16x8 __attribute__((ext_vector_type(8)));
typedef float  f32x4  __attribute__((ext_vector_type(4)));
typedef unsigned short ushortx8 __attribute__((ext_vector_type(8)));

// atom index map: N=0, C=1, Ca=2, Cb=3, O=4
__constant__ int c_pa[24] = {0,2,3,1,1,1,0,0,3,0,2,3,2,3,2,4,1,4,0,4,3,4,4,2};
__constant__ int c_pb[24] = {0,2,3,0,2,3,2,3,2,1,1,1,0,0,3,4,4,1,4,0,4,2,3,2};

__device__ __forceinline__ unsigned long long u64min(unsigned long long a, unsigned long long b) {
    return a < b ? a : b;
}
__device__ __forceinline__ unsigned long long u64max(unsigned long long a, unsigned long long b) {
    return a > b ? a : b;
}

__device__ __forceinline__ unsigned short f2bf(float f) {
    __hip_bfloat16 h = __float2bfloat16(f);
    return *(unsigned short*)&h;
}

// 8 RBF values starting at center mu0, spacing 4/3, sigma 1.25.
// 2-anchor form: v[0], v[4] by direct exp; two independent 3-step recurrences
// (halves the serial dependency depth vs the single 7-step chain).
// ratio at m: exp(2*d'*u0 - (2m-1)*d'^2), d'=16/15; decay c=exp(-2d'^2).
__device__ __forceinline__ void rbf8(float d, float mu0, float* v) {
    const float u0 = (d - mu0) * 0.8f;
    const float u4 = u0 - 4.2666667f;                       // u0 - 4*d'
    v[0] = __expf(-u0 * u0);
    v[4] = __expf(-u4 * u4);
    float ra = __expf(fmaf(2.1333333f, u0, -1.1377778f));   // exp(2d'u0 - d'^2)
    float rb = ra * 1.114178e-4f;                           // * exp(-8*d'^2)
    v[1] = v[0] * ra;  ra *= 0.10274083f;
    v[5] = v[4] * rb;  rb *= 0.10274083f;
    v[2] = v[1] * ra;  ra *= 0.10274083f;
    v[6] = v[5] * rb;  rb *= 0.10274083f;
    v[3] = v[2] * ra;
    v[7] = v[6] * rb;
}

// 16-lane rotate-add reduce via DPP (row_ror:N), all lanes end with the sum.
template<int CTRL>
__device__ __forceinline__ float dpp_radd(float x) {
    const int r = __builtin_amdgcn_update_dpp(0, __float_as_int(x), CTRL, 0xf, 0xf, true);
    return x + __int_as_float(r);
}
__device__ __forceinline__ float row16_sum(float x) {
    x = dpp_radd<0x121>(x);   // ror 1
    x = dpp_radd<0x122>(x);   // ror 2
    x = dpp_radd<0x124>(x);   // ror 4
    x = dpp_radd<0x128>(x);   // ror 8
    return x;
}

// ---------------- Kernel 1: top-k (blocks <1024) + W-prep (blocks >=1024) ---
__global__ __launch_bounds__(512) void topk5(
    const float* __restrict__ X, const float* __restrict__ mask,
    const float* __restrict__ Wg, unsigned short* __restrict__ Wt,
    int* __restrict__ eidx, float* __restrict__ dnb, float* __restrict__ outEidx)
{
#pragma clang fp contract(off)
    if (blockIdx.x >= 1024) {                  // ---- W transpose tail blocks ----
        const int id = (blockIdx.x - 1024) * 512 + threadIdx.x;  // 104*512 = 53248
        const int n = id / Fc, k = id - n * Fc;
        Wt[id] = f2bf(Wg[k * Nc + n]);
        return;
    }

    __shared__ float4 cp[Lc];                  // 32 KB packed C+mask for the batch
    __shared__ unsigned long long pairs[8][256];
    __shared__ int scnt[8];

    const int t = threadIdx.x;                 // 0..511
    const int lane = t & 63, wv = t >> 6;
    const int row = blockIdx.x * 8 + wv;       // b*L + i
    const int b   = blockIdx.x >> 8;           // 256 blocks per batch

    // --- stage packed batch slice ---
    #pragma unroll
    for (int s = 0; s < 4; ++s) {
        const int j = s * 512 + t;
        const float* p = X + (size_t)(b * Lc + j) * 12;
        float4 o;
        o.x = p[3]; o.y = p[4]; o.z = p[5];
        o.w = mask[b * Lc + j];
        cp[j] = o;
    }
    if (lane == 0) scnt[wv] = 0;
    __syncthreads();                           // the kernel's only barrier

    const float4 ci = cp[row & (Lc - 1)];
    const float cix = ci.x, ciy = ci.y, ciz = ci.z, mi = ci.w;

    // pass 1: distances from LDS, wave max
    float D[32], am[32];
    float dmax = -1e30f;
    #pragma unroll 8
    for (int s = 0; s < 32; ++s) {
        const float4 f4 = cp[s * 64 + lane];
        const float dx = f4.x - cix;
        const float dy = f4.y - ciy;
        const float dz = f4.z - ciz;
        const float ss = dx * dx + dy * dy + dz * dz;
        const float dist = sqrtf(ss + 1e-6f);
        const float m2 = mi * f4.w;
        D[s] = m2 * dist;
        am[s] = 1.0f - m2;
        dmax = fmaxf(dmax, D[s]);
    }
    #pragma unroll
    for (int off = 32; off; off >>= 1) dmax = fmaxf(dmax, __shfl_xor(dmax, off, 64));

    // pass 2: Dadj bits in registers; per-lane min key
    unsigned uv[32];
    unsigned long long lmin = ~0ULL;
    #pragma unroll 8
    for (int s = 0; s < 32; ++s) {
        const float Dadj = D[s] + am[s] * dmax;
        uv[s] = __float_as_uint(Dadj);
        const unsigned long long k =
            ((unsigned long long)uv[s] << 32) | (unsigned)(s * 64 + lane);
        lmin = u64min(lmin, k);
    }

    // bitonic sort of the 64 lane-min keys (ascending across lanes)
    unsigned long long sv = lmin;
    #pragma unroll
    for (int k = 2; k <= 64; k <<= 1) {
        #pragma unroll
        for (int j = k >> 1; j > 0; j >>= 1) {
            const unsigned long long o =
                (unsigned long long)__shfl_xor((long long)sv, j, 64);
            const bool takeMin = (((lane & k) == 0) == ((lane & j) == 0));
            sv = takeMin ? u64min(sv, o) : u64max(sv, o);
        }
    }
    const unsigned long long Tkey =
        (unsigned long long)__shfl((long long)sv, 29, 64);

    // gather survivors (key <= Tkey) into this wave's LDS list
    #pragma unroll 8
    for (int s = 0; s < 32; ++s) {
        const unsigned long long key =
            ((unsigned long long)uv[s] << 32) | (unsigned)(s * 64 + lane);
        if (key <= Tkey) {
            const int pos = atomicAdd(&scnt[wv], 1);
            if (pos < 256) pairs[wv][pos] = key;
        }
    }
    const int S = min(scnt[wv], 256);

    // exact rank among survivors; rank < 30 -> output slot = rank
    for (int p = lane; p < S; p += 64) {
        const unsigned long long kp = pairs[wv][p];
        int r = 0;
        for (int q = 0; q < S; ++q)
            r += (pairs[wv][q] < kp) ? 1 : 0;
        if (r < Kc) {
            const int j = (int)(kp & 0xffffffffULL);
            eidx[row * Kc + r] = j;
            dnb[row * Kc + r] = __uint_as_float((unsigned)(kp >> 32));
            outEidx[(size_t)row * Kc + r] = (float)j;
        }
    }
}

// ---------------- Kernel 2: 8-wave, 2-Mtile/wave MFMA GEMM + LayerNorm ------
// block = 8 residues (240 edges, M=256), 1024 blocks, 512 threads / 8 waves.
// Wave wv owns rows wv*32..wv*32+31 (two 16-row M-tiles) and all 8 N-tiles.
__global__ __launch_bounds__(512, 4) void edge_mfma7(
    const float* __restrict__ X, const int* __restrict__ ridx, const int* __restrict__ clab,
    const float* __restrict__ pe_w, const float* __restrict__ pe_b,
    const unsigned short* __restrict__ Wt,   // bf16 [128][416] (n-major)
    const float* __restrict__ ln_g, const float* __restrict__ ln_b,
    const int* __restrict__ eidx, const float* __restrict__ dnb,
    float* __restrict__ outE)
{
    __shared__ unsigned short Bs[2][8][512]; // [buf][n-tile][lane*8]
    __shared__ float atomsA[8][17];
    __shared__ float atomsB[240][17];
    __shared__ float dnb_s[240];
    __shared__ int   pid_s[240];

    const int blk = blockIdx.x;              // 1024
    const int t   = threadIdx.x;             // 0..511
    const int lane = t & 63, wv = t >> 6;    // 8 waves
    const int b   = blk >> 8;                // 256 blocks per batch
    const int cl  = lane & 15, q = lane >> 4;

    // --- staging: atoms + Cb for 8 residues and their 240 neighbors ---
    if (t < 248) {
        int j;
        float* dst;
        if (t < 240) {
            j = eidx[(blk * 8 + t / 30) * Kc + (t % 30)];
            dst = &atomsB[t][0];
            dnb_s[t] = dnb[(blk * 8 + t / 30) * Kc + (t % 30)];
            const int rowi = blk * 8 + t / 30;
            const int jg = b * Lc + j;
            const int off = ridx[rowi] - ridx[jg];
            const int ec  = (clab[rowi] == clab[jg]) ? 1 : 0;
            pid_s[t] = ec ? min(max(off + 32, 0), 64) : 65;
        } else {
            j = (blk * 8 + (t - 240)) & (Lc - 1);
            dst = &atomsA[t - 240][0];
        }
        const float* p = X + (size_t)(b * Lc + j) * 12;
        const float Nx = p[0],  Ny = p[1],  Nz = p[2];
        const float Cx = p[3],  Cy = p[4],  Cz = p[5];
        const float Cax = p[6], Cay = p[7], Caz = p[8];
        const float Ox = p[9],  Oy = p[10], Oz = p[11];
        const float bx = Cax - Nx, by = Cay - Ny, bz = Caz - Nz;
        const float cx = Cx - Cax, cy = Cy - Cay, cz = Cz - Caz;
        const float ax = by * cz - bz * cy;
        const float ay = bz * cx - bx * cz;
        const float az = bx * cy - by * cx;
        dst[0] = Nx;  dst[1] = Ny;  dst[2] = Nz;
        dst[3] = Cx;  dst[4] = Cy;  dst[5] = Cz;
        dst[6] = Cax; dst[7] = Cay; dst[8] = Caz;
        dst[9]  = -0.58273431f * ax + 0.56802827f * bx - 0.54067466f * cx + Cax;
        dst[10] = -0.58273431f * ay + 0.56802827f * by - 0.54067466f * cy + Cay;
        dst[11] = -0.58273431f * az + 0.56802827f * bz - 0.54067466f * cz + Caz;
        dst[12] = Ox; dst[13] = Oy; dst[14] = Oz;
    }

    // --- B staging geometry: wave wv stages n-tile wv, one 16B frag/thread ---
    const unsigned short* gW = Wt + (wv * 16 + cl) * Fc + q * 8;
    {
        *(ushortx8*)&Bs[0][wv][lane * 8] = *(const ushortx8*)gW;   // chunk 0
    }
    __syncthreads();

    f32x4 acc[2][8];
    #pragma unroll
    for (int m = 0; m < 2; ++m)
        #pragma unroll
        for (int n = 0; n < 8; ++n) acc[m][n] = (f32x4){0.f, 0.f, 0.f, 0.f};

    const int row0 = wv * 32 + cl;
    const int row1 = row0 + 16;
    const int e0 = min(row0, 239), e1 = min(row1, 239);
    const int r0 = e0 / 30,        r1 = e1 / 30;

    auto afrag = [&](int kc, int e, int r) -> bf16x8 {
        float v[8];
        if (kc == 0) {
            if (q < 2) {
                const int base = pid_s[e] * 16 + q * 8;
                const float4 p0 = *(const float4*)&pe_w[base];
                const float4 p1 = *(const float4*)&pe_w[base + 4];
                const float4 b0 = *(const float4*)&pe_b[q * 8];
                const float4 b1 = *(const float4*)&pe_b[q * 8 + 4];
                v[0] = p0.x + b0.x; v[1] = p0.y + b0.y;
                v[2] = p0.z + b0.z; v[3] = p0.w + b0.w;
                v[4] = p1.x + b1.x; v[5] = p1.y + b1.y;
                v[6] = p1.z + b1.z; v[7] = p1.w + b1.w;
            } else {
                rbf8(dnb_s[e], (q == 2) ? 2.0f : 12.6666667f, v);
            }
        } else {
            const int p  = 2 * kc - 2 + (q >> 1);
            const int a_ = c_pa[p], b_ = c_pb[p];
            const float dx = atomsA[r][a_ * 3 + 0] - atomsB[e][b_ * 3 + 0];
            const float dy = atomsA[r][a_ * 3 + 1] - atomsB[e][b_ * 3 + 1];
            const float dz = atomsA[r][a_ * 3 + 2] - atomsB[e][b_ * 3 + 2];
            const float d = sqrtf(dx * dx + dy * dy + dz * dz + 1e-6f);
            rbf8(d, (q & 1) ? 12.6666667f : 2.0f, v);
        }
        ushortx8 o;
        #pragma unroll
        for (int m = 0; m < 8; ++m) o[m] = f2bf(v[m]);
        return __builtin_bit_cast(bf16x8, o);
    };

    bf16x8 a0c = afrag(0, e0, r0);
    bf16x8 a1c = afrag(0, e1, r1);

    for (int kc = 0; kc < 13; ++kc) {
        const int cur = kc & 1;
        ushortx8 st;
        bf16x8 a0n, a1n;
        if (kc < 12) {
            st = *(const ushortx8*)(gW + (kc + 1) * 32);   // VMEM early
            a0n = afrag(kc + 1, e0, r0);                   // VALU overlaps MFMA
            a1n = afrag(kc + 1, e1, r1);
        }
        #pragma unroll
        for (int n = 0; n < 8; ++n) {
            const bf16x8 bb = __builtin_bit_cast(bf16x8,
                *(const ushortx8*)&Bs[cur][n][lane * 8]);
            acc[0][n] = __builtin_amdgcn_mfma_f32_16x16x32_bf16(a0c, bb, acc[0][n], 0, 0, 0);
            acc[1][n] = __builtin_amdgcn_mfma_f32_16x16x32_bf16(a1c, bb, acc[1][n], 0, 0, 0);
        }
        if (kc < 12) {                        // write-late
            *(ushortx8*)&Bs[cur ^ 1][wv][lane * 8] = st;
        }
        __syncthreads();
        a0c = a0n; a1c = a1n;
    }

    // ---------------- LayerNorm (DPP rotate-reduce) + store ----------------
    float gcol[8], bcol[8];
    #pragma unroll
    for (int n = 0; n < 8; ++n) {
        gcol[n] = ln_g[n * 16 + cl];
        bcol[n] = ln_b[n * 16 + cl];
    }
    #pragma unroll
    for (int m = 0; m < 2; ++m) {
        #pragma unroll
        for (int reg = 0; reg < 4; ++reg) {
            const int rl = wv * 32 + m * 16 + q * 4 + reg;
            float s1 = 0.f, s2 = 0.f;
            #pragma unroll
            for (int n = 0; n < 8; ++n) {
                const float v = acc[m][n][reg];
                s1 += v; s2 += v * v;
            }
            s1 = row16_sum(s1);
            s2 = row16_sum(s2);
            if (rl < 240) {
                const float mu = s1 * (1.0f / 128.0f);
                const float var = s2 * (1.0f / 128.0f) - mu * mu;
                const float rstd = rsqrtf(var + 1e-5f);
                const size_t base = ((size_t)(blk * 240 + rl)) * 128 + cl;
                #pragma unroll
                for (int n = 0; n < 8; ++n) {
                    outE[base + n * 16] =
                        (acc[m][n][reg] - mu) * rstd * gcol[n] + bcol[n];
                }
            }
        }
    }
}

extern "C" void kernel_launch(void* const* d_in, const int* in_sizes, int n_in,
                              void* d_out, int out_size, void* d_ws, size_t ws_size,
                              hipStream_t stream) {
    const float* X     = (const float*)d_in[0];
    const float* mask  = (const float*)d_in[1];
    const int*   ridx  = (const int*)d_in[2];
    const int*   clab  = (const int*)d_in[3];
    const float* pe_w  = (const float*)d_in[4];
    const float* pe_b  = (const float*)d_in[5];
    const float* edge_w = (const float*)d_in[6];
    const float* ln_g  = (const float*)d_in[7];
    const float* ln_b  = (const float*)d_in[8];

    float* outE   = (float*)d_out;
    float* outIdx = outE + (size_t)Bc * Lc * Kc * Nc;   // E_idx region (as float)

    char* ws = (char*)d_ws;
    int*   eidx = (int*)ws;                                  //   983,040 B
    float* dnbw = (float*)(ws + 983040);                     //   983,040 B
    unsigned short* Wt = (unsigned short*)(ws + 1966080);    //   106,496 B

    topk5<<<1024 + 104, 512, 0, stream>>>(X, mask, edge_w, Wt, eidx, dnbw, outIdx);
    edge_mfma7<<<Bc * Lc / 8, 512, 0, stream>>>(X, ridx, clab, pe_w, pe_b, Wt,
                                                ln_g, ln_b, eidx, dnbw, outE);
}